// Round 8
// baseline (1342.449 us; speedup 1.0000x reference)
//
#include <hip/hip_runtime.h>
#include <stdint.h>

#define D_MODEL 1024
#define SEQ 2048
#define NBATCH 4
#define GRIDN 1024   // 4 blocks/CU x 256 CUs; __launch_bounds__(256,4) guarantees co-residency

typedef __attribute__((ext_vector_type(4))) float f32x4;
typedef __attribute__((ext_vector_type(8))) __bf16 bf16x8;
typedef __attribute__((ext_vector_type(4))) unsigned short u16x4;

__device__ __forceinline__ float b2f(unsigned short u) {
    union { unsigned int i; float f; } c; c.i = ((unsigned int)u) << 16; return c.f;
}
__device__ __forceinline__ unsigned short f2b(float f) {
    union { float f; unsigned int i; } c; c.f = f;
    unsigned int u = c.i;
    u += 0x7FFFu + ((u >> 16) & 1u);
    return (unsigned short)(u >> 16);
}

__device__ __forceinline__ void glds16(void* lds, const void* g) {
    __builtin_amdgcn_global_load_lds((const __attribute__((address_space(1))) void*)g,
                                     (__attribute__((address_space(3))) void*)lds,
                                     16, 0, 0);
}

// Grid barrier for persistent blocks (all GRIDN co-resident by construction).
// slots[] live in d_ws: poisoned 0xAA (negative as int) or 0 — both < gen 1..5,
// so a SIGNED >= compare needs no explicit init. Store-release / load at agent
// scope + __threadfence keeps phase writes visible across non-coherent XCD L2s.
__device__ __forceinline__ void gridbar(int* slots, int gen)
{
    __threadfence();                 // flush this block's phase writes
    __syncthreads();
    const int t = threadIdx.x;
    if (t == 0)
        __hip_atomic_store(&slots[blockIdx.x], gen, __ATOMIC_RELEASE, __HIP_MEMORY_SCOPE_AGENT);
    for (;;) {
        int v0 = __hip_atomic_load(&slots[t],       __ATOMIC_RELAXED, __HIP_MEMORY_SCOPE_AGENT);
        int v1 = __hip_atomic_load(&slots[t + 256], __ATOMIC_RELAXED, __HIP_MEMORY_SCOPE_AGENT);
        int v2 = __hip_atomic_load(&slots[t + 512], __ATOMIC_RELAXED, __HIP_MEMORY_SCOPE_AGENT);
        int v3 = __hip_atomic_load(&slots[t + 768], __ATOMIC_RELAXED, __HIP_MEMORY_SCOPE_AGENT);
        if (v0 >= gen && v1 >= gen && v2 >= gen && v3 >= gen) break;
        __builtin_amdgcn_s_sleep(2);
    }
    __threadfence();                 // acquire side
    __syncthreads();
}

// R6 GEMM core (proven 711 TF): BK=64, both operands via LDS, glds staging,
// XOR swizzle (slot (row,c) holds chunk c^(row&7), permuted on the global
// source side; readers fetch (s*4+quad)^(fr&7)) -> 2-way banking (free).
// R7's A-direct-from-global variant regressed 1.7x (VMEM-latency-bound) — reverted.
__device__ __forceinline__ void gemm_tile(unsigned short* As, unsigned short* Bs,
                                          const unsigned short* __restrict__ A,
                                          const unsigned short* __restrict__ Bt,
                                          int K, int m0, int n0,
                                          f32x4 (&acc)[4][4])
{
    const int t    = threadIdx.x;
    const int wave = t >> 6;
    const int lane = t & 63;
    const int srow = t >> 3;
    const int sch  = ((t & 7) ^ (srow & 7)) * 8;

    const unsigned short* Ag = A  + (long)(m0 + srow) * K + sch;
    const unsigned short* Bg = Bt + (long)(n0 + srow) * K + sch;

    char* AsB = (char*)As + wave * 1024;        // wave-uniform glds base
    char* BsB = (char*)Bs + wave * 1024;

    const int wm   = (wave >> 1) * 64;
    const int wn   = (wave & 1) * 64;
    const int fr   = lane & 15;
    const int quad = lane >> 4;
    const int rp0  = ((quad    ) ^ (fr & 7)) * 16;
    const int rp1  = ((4 + quad) ^ (fr & 7)) * 16;

    for (int k0 = 0; k0 < K; k0 += 64) {
        __syncthreads();
        #pragma unroll
        for (int j = 0; j < 4; ++j) {
            glds16(AsB + j * 4096, Ag + (long)(j * 32) * K + k0);
            glds16(BsB + j * 4096, Bg + (long)(j * 32) * K + k0);
        }
        __syncthreads();

        #pragma unroll
        for (int s = 0; s < 2; ++s) {
            const int ro = s ? rp1 : rp0;
            bf16x8 af[4], bfv[4];
            #pragma unroll
            for (int i = 0; i < 4; ++i)
                af[i] = *(const bf16x8*)((const char*)As + (wm + i * 16 + fr) * 128 + ro);
            #pragma unroll
            for (int i = 0; i < 4; ++i)
                bfv[i] = *(const bf16x8*)((const char*)Bs + (wn + i * 16 + fr) * 128 + ro);

            #pragma unroll
            for (int mi = 0; mi < 4; ++mi)
                #pragma unroll
                for (int ni = 0; ni < 4; ++ni)
                    acc[mi][ni] = __builtin_amdgcn_mfma_f32_16x16x32_bf16(
                                      af[mi], bfv[ni], acc[mi][ni], 0, 0, 0);
        }
    }
}

// Epilogue variants. C/D layout (HW-verified): col = lane&15, row = quad*4 + reg.
// MODE 0: bf16 store      1: bf16 + bias      2: bf16 + bias, V-transposed store
// MODE 3: fp32 + bias
template<int MODE, typename OutT>
__device__ __forceinline__ void gemm_store(OutT* __restrict__ C, const float* __restrict__ bias,
                                           int N, int m0, int n0, f32x4 (&acc)[4][4])
{
    const int t = threadIdx.x, wave = t >> 6, lane = t & 63;
    const int wm = (wave >> 1) * 64, wn = (wave & 1) * 64;
    const int fr = lane & 15, quad = lane >> 4;

    float bb[4] = {0.f, 0.f, 0.f, 0.f};
    if (MODE != 0) {
        #pragma unroll
        for (int ni = 0; ni < 4; ++ni)
            bb[ni] = bias[n0 + wn + ni * 16 + fr];
    }

    #pragma unroll
    for (int mi = 0; mi < 4; ++mi) {
        const int rowb = m0 + wm + mi * 16 + quad * 4;
        #pragma unroll
        for (int ni = 0; ni < 4; ++ni) {
            const int col = n0 + wn + ni * 16 + fr;
            f32x4 v = acc[mi][ni];
            if constexpr (MODE == 3) {
                #pragma unroll
                for (int r = 0; r < 4; ++r)
                    C[(long)(rowb + r) * N + col] = v[r] + bb[ni];
            } else if constexpr (MODE == 2) {
                u16x4 pk;
                #pragma unroll
                for (int r = 0; r < 4; ++r)
                    pk[r] = f2b(v[r] + bb[ni]);
                unsigned short* dst = (unsigned short*)C
                                    + ((long)(rowb >> 11)) * ((long)N * SEQ)
                                    + (long)col * SEQ + (rowb & (SEQ - 1));
                *(u16x4*)dst = pk;
            } else {
                #pragma unroll
                for (int r = 0; r < 4; ++r)
                    C[(long)(rowb + r) * N + col] = (OutT)f2b(v[r] + bb[ni]);
            }
        }
    }
}

__global__ __launch_bounds__(256, 4)
void mega(const float* __restrict__ x,
          const float* __restrict__ Wq, const float* __restrict__ bq,
          const float* __restrict__ Wk, const float* __restrict__ bk,
          const float* __restrict__ Wv, const float* __restrict__ bv,
          const float* __restrict__ Wo, const float* __restrict__ bo,
          float* __restrict__ out, char* __restrict__ ws)
{
    const size_t MB = 1024ull * 1024ull;
    unsigned short* Wqt = (unsigned short*)(ws + 0 * MB);
    unsigned short* Wkt = (unsigned short*)(ws + 2 * MB);
    unsigned short* Wvt = (unsigned short*)(ws + 4 * MB);
    unsigned short* Wot = (unsigned short*)(ws + 6 * MB);
    unsigned short* xb  = (unsigned short*)(ws + 8 * MB);
    unsigned short* Q   = (unsigned short*)(ws + 24 * MB);
    unsigned short* Kb  = (unsigned short*)(ws + 40 * MB);
    unsigned short* Vt  = (unsigned short*)(ws + 56 * MB);
    unsigned short* At  = (unsigned short*)(ws + 72 * MB);
    unsigned short* S   = (unsigned short*)(ws + 88 * MB);
    int*            slots = (int*)(ws + 120 * MB);

    __shared__ alignas(16) unsigned char SMEM[32768];
    unsigned short* As = (unsigned short*)SMEM;
    unsigned short* Bs = (unsigned short*)(SMEM + 16384);

    const int bid = blockIdx.x;
    const int c   = bid & 7;       // XCD (dispatch is round-robin; persistent => pinned)
    const int lb  = bid >> 3;      // local block index within XCD, 0..127
    const int t   = threadIdx.x;

    // ---- phase 0: prep (cast x to bf16; transpose+cast 4 weights) ----
    for (int u = bid; u < 12288; u += GRIDN) {
        if (u < 8192) {
            long i = ((long)u * 256 + t) * 4;
            f32x4 v = *(const f32x4*)(x + i);
            u16x4 o;
            #pragma unroll
            for (int r = 0; r < 4; ++r) o[r] = f2b(v[r]);
            *(u16x4*)(xb + i) = o;
        } else {
            const int b2 = u - 8192;
            const float* W; unsigned short* T;
            switch (b2 >> 10) {
                case 0:  W = Wq; T = Wqt; break;
                case 1:  W = Wk; T = Wkt; break;
                case 2:  W = Wv; T = Wvt; break;
                default: W = Wo; T = Wot; break;
            }
            const int tile = b2 & 1023;
            const int bx = (tile & 31) * 32, by = (tile >> 5) * 32;
            float (*buf)[33] = (float(*)[33])SMEM;
            const int tx = t & 31, ty = t >> 5;
            __syncthreads();             // guard SMEM reuse across loop iters
            #pragma unroll
            for (int i = 0; i < 32; i += 8)
                buf[ty + i][tx] = W[(long)(by + ty + i) * D_MODEL + bx + tx];
            __syncthreads();
            #pragma unroll
            for (int i = 0; i < 32; i += 8)
                Wot[0] == 0 ? void() : void();  // no-op
            #pragma unroll
            for (int i = 0; i < 32; i += 8)
                T[(long)(bx + ty + i) * D_MODEL + by + tx] = f2b(buf[tx][ty + i]);
        }
    }
    gridbar(slots, 1);

    // ---- phase 1: QKV projections (192 tiles per XCD: 8y x 8x x 3z) ----
    for (int lt = lb; lt < 192; lt += 128) {
        const int yy = c * 8 + (lt & 7);
        const int xx = (lt >> 3) & 7;
        const int zz = lt >> 6;
        const unsigned short* Bt = (zz == 0) ? Wqt : (zz == 1) ? Wkt : Wvt;
        const float* bias        = (zz == 0) ? bq  : (zz == 1) ? bk  : bv;
        unsigned short* C        = (zz == 0) ? Q   : (zz == 1) ? Kb  : Vt;

        f32x4 acc[4][4] = {};
        gemm_tile(As, Bs, xb, Bt, D_MODEL, yy * 128, xx * 128, acc);
        if (zz == 2) gemm_store<2>(C, bias, D_MODEL, yy * 128, xx * 128, acc);
        else         gemm_store<1>(C, bias, D_MODEL, yy * 128, xx * 128, acc);
    }
    gridbar(slots, 2);

    // ---- phase 2: scores = Q @ K^T (128 tiles per XCD: 2y x 16x x 4z) ----
    {
        const int lt = lb;           // exactly one tile per block
        const int yy = c * 2 + (lt & 1);
        const int xx = (lt >> 1) & 15;
        const int zz = lt >> 5;
        const unsigned short* Aq = Q  + (long)zz * SEQ * D_MODEL;
        const unsigned short* Bk = Kb + (long)zz * SEQ * D_MODEL;
        unsigned short* Cs       = S  + (long)zz * SEQ * SEQ;

        f32x4 acc[4][4] = {};
        gemm_tile(As, Bs, Aq, Bk, D_MODEL, yy * 128, xx * 128, acc);
        gemm_store<0>(Cs, (const float*)nullptr, SEQ, yy * 128, xx * 128, acc);
    }
    gridbar(slots, 3);

    // ---- phase 3: softmax over 8192 rows of 2048 (scale 1/32 folded in) ----
    for (int r = bid; r < NBATCH * SEQ; r += GRIDN) {
        unsigned short* s = S + (long)r * SEQ;
        float* red = (float*)SMEM;

        u16x4 a = ((const u16x4*)s)[t];
        u16x4 b = ((const u16x4*)s)[t + 256];
        float v[8];
        #pragma unroll
        for (int i = 0; i < 4; ++i) { v[i] = b2f(a[i]); v[4 + i] = b2f(b[i]); }

        float mx = v[0];
        #pragma unroll
        for (int i = 1; i < 8; ++i) mx = fmaxf(mx, v[i]);
        #pragma unroll
        for (int off = 32; off; off >>= 1) mx = fmaxf(mx, __shfl_xor(mx, off));

        const int wv = t >> 6, ln = t & 63;
        if (ln == 0) red[wv] = mx;
        __syncthreads();
        mx = fmaxf(fmaxf(red[0], red[1]), fmaxf(red[2], red[3]));

        const float sc = 0.03125f;
        float e[8], sum = 0.f;
        #pragma unroll
        for (int i = 0; i < 8; ++i) { e[i] = __expf((v[i] - mx) * sc); sum += e[i]; }
        #pragma unroll
        for (int off = 32; off; off >>= 1) sum += __shfl_xor(sum, off);
        if (ln == 0) red[4 + wv] = sum;
        __syncthreads();
        sum = (red[4] + red[5]) + (red[6] + red[7]);
        const float inv = 1.f / sum;

        u16x4 o;
        #pragma unroll
        for (int i = 0; i < 4; ++i) o[i] = f2b(e[i] * inv);
        ((u16x4*)s)[t] = o;
        #pragma unroll
        for (int i = 0; i < 4; ++i) o[i] = f2b(e[4 + i] * inv);
        ((u16x4*)s)[t + 256] = o;
    }
    gridbar(slots, 4);

    // ---- phase 4: attn = P @ V (64 tiles per XCD: 2y x 8x x 4z) ----
    if (lb < 64) {
        const int lt = lb;
        const int yy = c * 2 + (lt & 1);
        const int xx = (lt >> 1) & 7;
        const int zz = lt >> 4;
        const unsigned short* Ap = S  + (long)zz * SEQ * SEQ;
        const unsigned short* Bv = Vt + (long)zz * D_MODEL * SEQ;
        unsigned short* Ca       = At + (long)zz * SEQ * D_MODEL;

        f32x4 acc[4][4] = {};
        gemm_tile(As, Bs, Ap, Bv, SEQ, yy * 128, xx * 128, acc);
        gemm_store<0>(Ca, (const float*)nullptr, D_MODEL, yy * 128, xx * 128, acc);
    }
    gridbar(slots, 5);

    // ---- phase 5: out = attn @ Wo + bo (64 tiles per XCD: 8y x 8x) ----
    if (lb < 64) {
        const int lt = lb;
        const int yy = c * 8 + (lt & 7);
        const int xx = lt >> 3;

        f32x4 acc[4][4] = {};
        gemm_tile(As, Bs, At, Wot, D_MODEL, yy * 128, xx * 128, acc);
        gemm_store<3>(out, bo, D_MODEL, yy * 128, xx * 128, acc);
    }
}

extern "C" void kernel_launch(void* const* d_in, const int* in_sizes, int n_in,
                              void* d_out, int out_size, void* d_ws, size_t ws_size,
                              hipStream_t stream)
{
    const float* x  = (const float*)d_in[0];
    const float* Wq = (const float*)d_in[1];
    const float* bq = (const float*)d_in[2];
    const float* Wk = (const float*)d_in[3];
    const float* bk = (const float*)d_in[4];
    const float* Wv = (const float*)d_in[5];
    const float* bv = (const float*)d_in[6];
    const float* Wo = (const float*)d_in[7];
    const float* bo = (const float*)d_in[8];

    mega<<<dim3(GRIDN), dim3(256), 0, stream>>>(
        x, Wq, bq, Wk, bk, Wv, bv, Wo, bo, (float*)d_out, (char*)d_ws);
}